// Round 4
// baseline (212.435 us; speedup 1.0000x reference)
//
#include <hip/hip_runtime.h>

// Inputs: [32,3,512,512] f32; pooled grid 128x128 per image.
#define HH 512
#define WW 512
#define PH 128
#define PW 128
#define CC 3

typedef float f32x4 __attribute__((ext_vector_type(4)));

// R8: global_load_lds DMA read path (Theory D).
//
// R0-R7: 8 structures, all reading via global_load_dwordx4 -> VGPR, all clamp
// at 2.76-2.9 TB/s read while write-only fills sustain 6.85 TB/s. R7's
// counters: pool 73us, VALUBusy 2.5%, occupancy 55% -- not VALU, not
// occupancy, not stream layout. Remaining suspect: the TA/TCP->VGPR load
// return path. This kernel reads through the ONLY other global-read path on
// gfx950: VMEM->LDS DMA (global_load_lds, width=16, no VGPR writeback,
// 1 instr per 1KB per wave), double-buffered with counted vmcnt(4) + raw
// s_barrier (m201 pattern; __syncthreads would drain the prefetch queue).
//
// Block bid owns pooled rows {2*(bid&63), +1} of image bid>>6: 8 image rows
// x 2KB x 6 planes = six contiguous 16KB chunks. Stage chunk s+1 while
// reducing chunk s from LDS (ds_read_b128, conflict-free 16B/lane pattern).
__global__ void __launch_bounds__(256)
pool_diff_kernel(const float* __restrict__ orig,
                 const float* __restrict__ enh,
                 float* __restrict__ g) {
    __shared__ f32x4 buf[2][1024];      // 2 x 16KB double buffer

    const int bid  = blockIdx.x;        // 0..2047
    const int t    = threadIdx.x;       // 0..255
    const int wave = t >> 6;            // 0..3
    const int lane = t & 63;
    const int half = t >> 7;            // row parity within pooled-row pair
    const int pj   = t & 127;           // pooled column

    const int b    = bid >> 6;          // image 0..31
    const int pr0  = (bid & 63) * 2;    // first pooled row
    const int row0 = pr0 * 4;           // first image row (8 rows)

    const size_t img = (size_t)HH * WW; // 262144

    // Stage chunk s2 (16KB contiguous) into buf[pb]: 16 wave-instrs x 1KB.
    // LDS dest is wave-uniform base; HW adds lane*16. Global src is per-lane.
    auto stage = [&](int pb, int s2) {
        const int    c    = (s2 < 3) ? s2 : s2 - 3;
        const float* src  = (s2 < 3) ? orig : enh;
        const float* base = src + ((size_t)b * CC + c) * img + (size_t)row0 * WW;
        float*       lb   = (float*)&buf[pb][0];
#pragma unroll
        for (int q = 0; q < 4; ++q) {
            const int unit = wave * 4 + q;          // 0..15, uniform per wave
            __builtin_amdgcn_global_load_lds(
                (const __attribute__((address_space(1))) void*)(base + unit * 256 + lane * 4),
                (__attribute__((address_space(3))) void*)(lb + unit * 256),
                16, 0, 0);
        }
    };

    float acc0 = 0.0f, acc1 = 0.0f;

    stage(0, 0);                                    // prologue: 4 loads/wave
#pragma unroll
    for (int s = 0; s < 6; ++s) {
        const int pb = s & 1;
        if (s < 5) {
            stage(pb ^ 1, s + 1);                   // prefetch: +4 loads/wave
            asm volatile("s_waitcnt vmcnt(4)" ::: "memory");  // chunk s landed
        } else {
            asm volatile("s_waitcnt vmcnt(0)" ::: "memory");
        }
        __builtin_amdgcn_sched_barrier(0);
        __builtin_amdgcn_s_barrier();               // chunk s visible block-wide
        __builtin_amdgcn_sched_barrier(0);

        // Reduce chunk s: rows {half,2+half} -> acc0, {4+half,6+half} -> acc1.
        const f32x4* B = &buf[pb][0];
        f32x4 v0 = B[(0 + half) * 128 + pj];
        f32x4 v1 = B[(2 + half) * 128 + pj];
        f32x4 v2 = B[(4 + half) * 128 + pj];
        f32x4 v3 = B[(6 + half) * 128 + pj];
        const float s01 = ((v0.x + v0.y) + (v0.z + v0.w))
                        + ((v1.x + v1.y) + (v1.z + v1.w));
        const float s23 = ((v2.x + v2.y) + (v2.z + v2.w))
                        + ((v3.x + v3.y) + (v3.z + v3.w));
        if (s < 3) { acc0 += s01; acc1 += s23; }
        else       { acc0 -= s01; acc1 -= s23; }

        asm volatile("s_waitcnt lgkmcnt(0)" ::: "memory");  // ds_reads done
        __builtin_amdgcn_sched_barrier(0);
        __builtin_amdgcn_s_barrier();               // safe to re-stage buf[pb]
    }

    // Combine halves (reuse buf[0] as scratch; all DMA/ds ops drained above).
    float* cb = (float*)&buf[0][0];
    cb[t]       = acc0;
    cb[256 + t] = acc1;
    __syncthreads();
    if (t < 128) {
        g[((size_t)b * PH + pr0) * PW + t] = (cb[t] + cb[t + 128]) * (1.0f / 48.0f);
    } else {
        const int tj = t - 128;
        g[((size_t)b * PH + pr0 + 1) * PW + tj] = (cb[256 + tj] + cb[256 + t]) * (1.0f / 48.0f);
    }
}

// Kernel 2: loss[i,j] = sum over {l,r,u,d} of (g[i,j] - g_pad[neighbor])^2
// Zero padding: out-of-bounds neighbor contributes 0 (so diff = g[i,j]).
__global__ void __launch_bounds__(256)
stencil_loss_kernel(const float* __restrict__ g,
                    float* __restrict__ out, int total) {
    int idx = blockIdx.x * blockDim.x + threadIdx.x;
    if (idx >= total) return;
    int j = idx & (PW - 1);
    int i = (idx >> 7) & (PH - 1);

    float c = g[idx];
    float l = (j > 0)      ? g[idx - 1]  : 0.0f;
    float r = (j < PW - 1) ? g[idx + 1]  : 0.0f;
    float u = (i > 0)      ? g[idx - PW] : 0.0f;
    float d = (i < PH - 1) ? g[idx + PW] : 0.0f;

    float dl = c - l, dr = c - r, du = c - u, dd = c - d;
    __builtin_nontemporal_store(dl * dl + dr * dr + du * du + dd * dd, out + idx);
}

extern "C" void kernel_launch(void* const* d_in, const int* in_sizes, int n_in,
                              void* d_out, int out_size, void* d_ws, size_t ws_size,
                              hipStream_t stream) {
    const float* orig = (const float*)d_in[0];
    const float* enh  = (const float*)d_in[1];
    float* out = (float*)d_out;
    float* g   = (float*)d_ws;  // 32*128*128 floats = 2 MB scratch

    const int batch = in_sizes[0] / (CC * HH * WW);   // 32
    const int total = batch * PH * PW;                // 524288

    // One block per pooled-row pair: 32 images * 64 pairs = 2048 blocks.
    pool_diff_kernel<<<batch * 64, 256, 0, stream>>>(orig, enh, g);

    const int block = 256;
    const int grid = (total + block - 1) / block;     // 2048
    stencil_loss_kernel<<<grid, block, 0, stream>>>(g, out, total);
}